// Round 1
// baseline (541.014 us; speedup 1.0000x reference)
//
#include <hip/hip_runtime.h>
#include <hip/hip_bf16.h>

#define H 2048
#define NH 32
#define HD 64
#define BB 2
#define SS 2048
#define MM (BB*SS)   // 4096 rows

typedef __attribute__((ext_vector_type(8))) short bf16x8;
typedef __attribute__((ext_vector_type(4))) float f32x4;
typedef unsigned short u16;
typedef unsigned int u32;

static __device__ __forceinline__ u16 f2bf(float f){
  union { float f; u32 i; } v; v.f = f;
  u32 x = v.i;
  return (u16)((x + 0x7FFFu + ((x >> 16) & 1u)) >> 16);  // RNE
}
static __device__ __forceinline__ float bf2f(u16 u){
  union { u32 i; float f; } v; v.i = ((u32)u) << 16; return v.f;
}

static __device__ __forceinline__ void gload16(const u16* g, u16* l){
  __builtin_amdgcn_global_load_lds((const __attribute__((address_space(1))) void*)g,
                                   (__attribute__((address_space(3))) void*)l, 16, 0, 0);
}

// ---------------- 1. X f32 -> bf16 ----------------
__global__ void k_cvt(const float* __restrict__ src, u16* __restrict__ dst){
  const int i = (blockIdx.x * 256 + threadIdx.x) * 4;
  float4 v = *(const float4*)(src + i);
  ushort4 o;
  o.x = f2bf(v.x); o.y = f2bf(v.y); o.z = f2bf(v.z); o.w = f2bf(v.w);
  *(ushort4*)(dst + i) = o;
}

// ---------------- 2. W [K][N] f32 -> Wt [N][K] bf16 ----------------
__global__ void k_wtrans(const float* __restrict__ w0, const float* __restrict__ w1,
                         const float* __restrict__ w2, const float* __restrict__ w3,
                         u16* __restrict__ d0, u16* __restrict__ d1,
                         u16* __restrict__ d2, u16* __restrict__ d3){
  __shared__ float tile[32][33];
  const int z = blockIdx.z;
  const float* w = z==0 ? w0 : z==1 ? w1 : z==2 ? w2 : w3;
  u16* d        = z==0 ? d0 : z==1 ? d1 : z==2 ? d2 : d3;
  const int n0 = blockIdx.x * 32, k0 = blockIdx.y * 32;
  const int tx = threadIdx.x, ty = threadIdx.y;  // 32 x 8
  #pragma unroll
  for (int j = 0; j < 4; j++)
    tile[ty + 8*j][tx] = w[(size_t)(k0 + ty + 8*j) * H + n0 + tx];
  __syncthreads();
  #pragma unroll
  for (int j = 0; j < 4; j++)
    d[(size_t)(n0 + ty + 8*j) * H + k0 + tx] = f2bf(tile[tx][ty + 8*j]);
}

// ---------------- 3/6. GEMM C[M][N] = A[M][K] * Bt[N][K]^T ----------------
// 128x128 tile, BK=64, 256 threads (4 waves, 2x2 of 64x64), mfma 16x16x32 bf16.
template<typename OutT>
__global__ __launch_bounds__(256, 2) void k_gemm(
    const u16* __restrict__ A,
    const u16* __restrict__ B0, const u16* __restrict__ B1, const u16* __restrict__ B2,
    OutT* __restrict__ C0, OutT* __restrict__ C1, OutT* __restrict__ C2,
    int M, int N, int K){
  __shared__ __align__(16) u16 As[128][64];
  __shared__ __align__(16) u16 Bs[128][64];
  const int z = blockIdx.z;
  const u16* Bt = z==0 ? B0 : z==1 ? B1 : B2;
  OutT* C       = z==0 ? C0 : z==1 ? C1 : C2;
  const int t = threadIdx.x;
  const int w = t >> 6, l = t & 63;
  const int m0 = blockIdx.x * 128, n0 = blockIdx.y * 128;
  const int srow = t >> 3, scol = (t & 7) * 8;      // staging: 32 rows x 8 chunks
  const int lrow = l & 15, lk = (l >> 4) * 8;       // fragment lane mapping
  const int wr = (w >> 1) * 64, wc = (w & 1) * 64;  // wave tile
  f32x4 acc[4][4] = {};
  for (int k0 = 0; k0 < K; k0 += 64){
    __syncthreads();
    #pragma unroll
    for (int c = 0; c < 4; c++)
      gload16(A + (size_t)(m0 + c*32 + srow) * K + k0 + scol, &As[c*32 + srow][scol]);
    #pragma unroll
    for (int c = 0; c < 4; c++)
      gload16(Bt + (size_t)(n0 + c*32 + srow) * K + k0 + scol, &Bs[c*32 + srow][scol]);
    __syncthreads();
    #pragma unroll
    for (int kk = 0; kk < 2; kk++){
      bf16x8 a[4], b[4];
      #pragma unroll
      for (int m = 0; m < 4; m++) a[m] = *(const bf16x8*)&As[wr + m*16 + lrow][kk*32 + lk];
      #pragma unroll
      for (int n = 0; n < 4; n++) b[n] = *(const bf16x8*)&Bs[wc + n*16 + lrow][kk*32 + lk];
      #pragma unroll
      for (int m = 0; m < 4; m++)
        #pragma unroll
        for (int n = 0; n < 4; n++)
          acc[m][n] = __builtin_amdgcn_mfma_f32_16x16x32_bf16(a[m], b[n], acc[m][n], 0, 0, 0);
    }
  }
  #pragma unroll
  for (int m = 0; m < 4; m++)
    #pragma unroll
    for (int n = 0; n < 4; n++)
      #pragma unroll
      for (int r = 0; r < 4; r++){
        const int row = m0 + wr + m*16 + (l >> 4)*4 + r;
        const int col = n0 + wc + n*16 + lrow;
        const float v = acc[m][n][r];
        if constexpr (sizeof(OutT) == 2) C[(size_t)row * N + col] = (OutT)f2bf(v);
        else                             C[(size_t)row * N + col] = v;
      }
}

// ---------------- 4. RoPE on Q (with 1/sqrt(HD) scale) and K, in place ----------------
__global__ void k_rope(u16* __restrict__ Q, u16* __restrict__ Kp){
  const int idx = blockIdx.x * 256 + threadIdx.x;  // 4096*32*4 threads
  const int quad = idx & 3;
  const int h = (idx >> 2) & 31;
  const int row = idx >> 7;
  const int s = row & (SS - 1);
  const int i0 = quad * 8;
  u16* q = Q  + (size_t)row * H + h * HD;
  u16* k = Kp + (size_t)row * H + h * HD;
  uint4 q1v = *(const uint4*)(q + i0);
  uint4 q2v = *(const uint4*)(q + i0 + 32);
  uint4 k1v = *(const uint4*)(k + i0);
  uint4 k2v = *(const uint4*)(k + i0 + 32);
  u16* q1 = (u16*)&q1v; u16* q2 = (u16*)&q2v;
  u16* k1 = (u16*)&k1v; u16* k2 = (u16*)&k2v;
  const float sf = (float)s;
  #pragma unroll
  for (int e = 0; e < 8; e++){
    const int i = i0 + e;
    const float inv = exp2f(-0.4152410118609203f * (float)i);  // 10000^(-i/32)
    float rev = sf * inv * 0.15915494309189535f;               // radians -> revolutions
    rev -= floorf(rev);
    const float sn = __builtin_amdgcn_sinf(rev);
    const float cs = __builtin_amdgcn_cosf(rev);
    const float qa = bf2f(q1[e]), qb = bf2f(q2[e]);
    q1[e] = f2bf((qa*cs - qb*sn) * 0.125f);
    q2[e] = f2bf((qb*cs + qa*sn) * 0.125f);
    const float ka = bf2f(k1[e]), kb = bf2f(k2[e]);
    k1[e] = f2bf(ka*cs - kb*sn);
    k2[e] = f2bf(kb*cs + ka*sn);
  }
  *(uint4*)(q + i0)      = q1v;
  *(uint4*)(q + i0 + 32) = q2v;
  *(uint4*)(k + i0)      = k1v;
  *(uint4*)(k + i0 + 32) = k2v;
}

// ---------------- 5. causal flash attention ----------------
// block = 256 thr (4 waves x 16 q-rows), QBLK=64, KVBLK=64.
__global__ __launch_bounds__(256, 2) void k_attn(
    const u16* __restrict__ Q, const u16* __restrict__ K,
    const u16* __restrict__ V, u16* __restrict__ O){
  __shared__ __align__(16) u16 Qs[64][64];
  __shared__ __align__(16) u16 Ks[64][64];
  __shared__ __align__(16) u16 Vs[64][72];      // transposed: Vs[d][j], padded
  __shared__ __align__(16) u16 Ps[4][16][72];   // per-wave P tile, padded
  const int t = threadIdx.x, w = t >> 6, l = t & 63;
  const int qt = blockIdx.x, bh = blockIdx.y;
  const int b = bh >> 5, h = bh & 31;
  const int q0 = qt * 64;
  const u16* qp = Q + (size_t)(b*SS + q0) * H + h * HD;
  const u16* kp = K + (size_t)(b*SS) * H + h * HD;
  const u16* vp = V + (size_t)(b*SS) * H + h * HD;
  const int srow = t >> 3, scol = (t & 7) * 8;
  const int lrow = l & 15, lk = (l >> 4) * 8;

  #pragma unroll
  for (int c = 0; c < 2; c++)
    gload16(qp + (size_t)(c*32 + srow) * H + scol, &Qs[c*32 + srow][scol]);
  __syncthreads();
  bf16x8 qa[2];
  qa[0] = *(const bf16x8*)&Qs[w*16 + lrow][lk];
  qa[1] = *(const bf16x8*)&Qs[w*16 + lrow][32 + lk];

  float mrun[4], lrun[4];
  f32x4 oacc[4] = {};
  #pragma unroll
  for (int r = 0; r < 4; r++){ mrun[r] = -1e30f; lrun[r] = 0.f; }

  for (int jt = 0; jt <= qt; jt++){
    const int j0 = jt * 64;
    __syncthreads();   // previous iter's LDS reads complete
    #pragma unroll
    for (int c = 0; c < 2; c++)
      gload16(kp + (size_t)(j0 + c*32 + srow) * H + scol, &Ks[c*32 + srow][scol]);
    #pragma unroll
    for (int c = 0; c < 2; c++){
      const int j = c*32 + srow;
      uint4 vv = *(const uint4*)(vp + (size_t)(j0 + j) * H + scol);
      const u16* pv = (const u16*)&vv;
      #pragma unroll
      for (int e = 0; e < 8; e++) Vs[scol + e][j] = pv[e];   // transpose into LDS
    }
    __syncthreads();

    // S = Q K^T  (16 q-rows x 64 j per wave)
    f32x4 sv[4] = {};
    #pragma unroll
    for (int kk = 0; kk < 2; kk++){
      bf16x8 kb[4];
      #pragma unroll
      for (int n = 0; n < 4; n++) kb[n] = *(const bf16x8*)&Ks[n*16 + lrow][kk*32 + lk];
      #pragma unroll
      for (int n = 0; n < 4; n++)
        sv[n] = __builtin_amdgcn_mfma_f32_16x16x32_bf16(qa[kk], kb[n], sv[n], 0, 0, 0);
    }
    if (jt == qt){  // diagonal tile: mask j > q
      const int qr = w*16 + (l >> 4)*4;
      #pragma unroll
      for (int n = 0; n < 4; n++)
        #pragma unroll
        for (int r = 0; r < 4; r++)
          if (n*16 + lrow > qr + r) sv[n][r] = -1e30f;
    }
    // online softmax (row lives in 16-lane group, 4 rows per lane via reg idx)
    float tmax[4], fac[4], rsum[4];
    #pragma unroll
    for (int r = 0; r < 4; r++)
      tmax[r] = fmaxf(fmaxf(sv[0][r], sv[1][r]), fmaxf(sv[2][r], sv[3][r]));
    #pragma unroll
    for (int off = 1; off < 16; off <<= 1)
      #pragma unroll
      for (int r = 0; r < 4; r++)
        tmax[r] = fmaxf(tmax[r], __shfl_xor(tmax[r], off, 64));
    #pragma unroll
    for (int r = 0; r < 4; r++){
      const float mn = fmaxf(mrun[r], tmax[r]);
      fac[r] = __expf(mrun[r] - mn);
      mrun[r] = mn;
    }
    #pragma unroll
    for (int n = 0; n < 4; n++)
      #pragma unroll
      for (int r = 0; r < 4; r++)
        sv[n][r] = __expf(sv[n][r] - mrun[r]);
    #pragma unroll
    for (int r = 0; r < 4; r++) rsum[r] = sv[0][r] + sv[1][r] + sv[2][r] + sv[3][r];
    #pragma unroll
    for (int off = 1; off < 16; off <<= 1)
      #pragma unroll
      for (int r = 0; r < 4; r++) rsum[r] += __shfl_xor(rsum[r], off, 64);
    #pragma unroll
    for (int r = 0; r < 4; r++) lrun[r] = lrun[r] * fac[r] + rsum[r];
    #pragma unroll
    for (int n = 0; n < 4; n++)
      #pragma unroll
      for (int r = 0; r < 4; r++) oacc[n][r] *= fac[r];
    // P (C-layout) -> LDS -> A-frag layout
    #pragma unroll
    for (int n = 0; n < 4; n++)
      #pragma unroll
      for (int r = 0; r < 4; r++)
        Ps[w][(l >> 4)*4 + r][n*16 + lrow] = f2bf(sv[n][r]);
    __syncthreads();
    // O += P V
    #pragma unroll
    for (int kk = 0; kk < 2; kk++){
      bf16x8 pa = *(const bf16x8*)&Ps[w][lrow][kk*32 + lk];
      #pragma unroll
      for (int n = 0; n < 4; n++){
        bf16x8 vb = *(const bf16x8*)&Vs[n*16 + lrow][kk*32 + lk];
        oacc[n] = __builtin_amdgcn_mfma_f32_16x16x32_bf16(pa, vb, oacc[n], 0, 0, 0);
      }
    }
  }
  u16* op = O + (size_t)(b*SS + q0 + w*16) * H + h * HD;
  #pragma unroll
  for (int n = 0; n < 4; n++)
    #pragma unroll
    for (int r = 0; r < 4; r++){
      const float val = oacc[n][r] / lrun[r];
      op[(size_t)((l >> 4)*4 + r) * H + n*16 + lrow] = f2bf(val);
    }
}

extern "C" void kernel_launch(void* const* d_in, const int* in_sizes, int n_in,
                              void* d_out, int out_size, void* d_ws, size_t ws_size,
                              hipStream_t stream){
  (void)in_sizes; (void)n_in; (void)out_size; (void)ws_size;
  const float* hs = (const float*)d_in[0];
  // d_in[1] = attention_mask (causal, implemented analytically)
  const float* wq = (const float*)d_in[2];
  const float* wk = (const float*)d_in[3];
  const float* wv = (const float*)d_in[4];
  const float* wo = (const float*)d_in[5];
  float* out = (float*)d_out;
  char* ws = (char*)d_ws;

  // workspace layout (bytes): Xb 16.8M | Wqt/Wkt/Wvt/Wot 4x8.4M | Vb 16.8M | Ob 16.8M  (~80MB)
  u16* Xb  = (u16*)ws;
  u16* Wqt = (u16*)(ws + (size_t)MM * H * 2);
  u16* Wkt = Wqt + (size_t)H * H;
  u16* Wvt = Wkt + (size_t)H * H;
  u16* Wot = Wvt + (size_t)H * H;
  u16* Vb  = Wot + (size_t)H * H;
  u16* Ob  = Vb  + (size_t)MM * H;
  // Q,K (bf16) live in d_out's 33.5MB until the final GEMM overwrites it
  u16* Qb  = (u16*)d_out;
  u16* Kb  = Qb + (size_t)MM * H;

  k_cvt<<<8192, 256, 0, stream>>>(hs, Xb);
  k_wtrans<<<dim3(64, 64, 4), dim3(32, 8), 0, stream>>>(wq, wk, wv, wo, Wqt, Wkt, Wvt, Wot);
  k_gemm<u16><<<dim3(32, 16, 3), 256, 0, stream>>>(Xb, Wqt, Wkt, Wvt, Qb, Kb, Vb, MM, H, H);
  k_rope<<<2048, 256, 0, stream>>>(Qb, Kb);
  k_attn<<<dim3(32, 64), 256, 0, stream>>>(Qb, Kb, Vb, Ob);
  k_gemm<float><<<dim3(32, 16, 1), 256, 0, stream>>>(Ob, Wot, Wot, Wot, out, out, out, MM, H, H);
}

// Round 2
// 343.404 us; speedup vs baseline: 1.5754x; 1.5754x over previous
//
#include <hip/hip_runtime.h>
#include <hip/hip_bf16.h>

#define H 2048
#define NH 32
#define HD 64
#define BB 2
#define SS 2048
#define MM (BB*SS)   // 4096 rows

typedef __attribute__((ext_vector_type(8))) short bf16x8;
typedef __attribute__((ext_vector_type(4))) float f32x4;
typedef unsigned short u16;
typedef unsigned int u32;

static __device__ __forceinline__ u16 f2bf(float f){
  union { float f; u32 i; } v; v.f = f;
  u32 x = v.i;
  return (u16)((x + 0x7FFFu + ((x >> 16) & 1u)) >> 16);  // RNE
}
static __device__ __forceinline__ float bf2f(u16 u){
  union { u32 i; float f; } v; v.i = ((u32)u) << 16; return v.f;
}

static __device__ __forceinline__ void gload16(const u16* g, u16* l){
  __builtin_amdgcn_global_load_lds((const __attribute__((address_space(1))) void*)g,
                                   (__attribute__((address_space(3))) void*)l, 16, 0, 0);
}

// ---------------- 1. X f32 -> bf16 ----------------
__global__ void k_cvt(const float* __restrict__ src, u16* __restrict__ dst){
  const int i = (blockIdx.x * 256 + threadIdx.x) * 4;
  float4 v = *(const float4*)(src + i);
  ushort4 o;
  o.x = f2bf(v.x); o.y = f2bf(v.y); o.z = f2bf(v.z); o.w = f2bf(v.w);
  *(ushort4*)(dst + i) = o;
}

// ---------------- 2. W [K][N] f32 -> Wt [N][K] bf16 ----------------
__global__ void k_wtrans(const float* __restrict__ w0, const float* __restrict__ w1,
                         const float* __restrict__ w2, const float* __restrict__ w3,
                         u16* __restrict__ d0, u16* __restrict__ d1,
                         u16* __restrict__ d2, u16* __restrict__ d3){
  __shared__ float tile[32][33];
  const int z = blockIdx.z;
  const float* w = z==0 ? w0 : z==1 ? w1 : z==2 ? w2 : w3;
  u16* d        = z==0 ? d0 : z==1 ? d1 : z==2 ? d2 : d3;
  const int n0 = blockIdx.x * 32, k0 = blockIdx.y * 32;
  const int tx = threadIdx.x, ty = threadIdx.y;  // 32 x 8
  #pragma unroll
  for (int j = 0; j < 4; j++)
    tile[ty + 8*j][tx] = w[(size_t)(k0 + ty + 8*j) * H + n0 + tx];
  __syncthreads();
  #pragma unroll
  for (int j = 0; j < 4; j++)
    d[(size_t)(n0 + ty + 8*j) * H + k0 + tx] = f2bf(tile[tx][ty + 8*j]);
}

// ---------------- 3/6. GEMM C[M][N] = A[M][K] * Bt[N][K]^T ----------------
// 128x128 tile, BK=64, 256 threads (4 waves, 2x2 of 64x64), mfma 16x16x32 bf16.
template<typename OutT>
__global__ __launch_bounds__(256, 2) void k_gemm(
    const u16* __restrict__ A,
    const u16* __restrict__ B0, const u16* __restrict__ B1, const u16* __restrict__ B2,
    OutT* __restrict__ C0, OutT* __restrict__ C1, OutT* __restrict__ C2,
    int M, int N, int K){
  __shared__ __align__(16) u16 As[128][64];
  __shared__ __align__(16) u16 Bs[128][64];
  const int z = blockIdx.z;
  const u16* Bt = z==0 ? B0 : z==1 ? B1 : B2;
  OutT* C       = z==0 ? C0 : z==1 ? C1 : C2;
  const int t = threadIdx.x;
  const int w = t >> 6, l = t & 63;
  const int m0 = blockIdx.x * 128, n0 = blockIdx.y * 128;
  const int srow = t >> 3, scol = (t & 7) * 8;      // staging: 32 rows x 8 chunks
  const int lrow = l & 15, lk = (l >> 4) * 8;       // fragment lane mapping
  const int wr = (w >> 1) * 64, wc = (w & 1) * 64;  // wave tile
  f32x4 acc[4][4] = {};
  for (int k0 = 0; k0 < K; k0 += 64){
    __syncthreads();
    #pragma unroll
    for (int c = 0; c < 4; c++)
      gload16(A + (size_t)(m0 + c*32 + srow) * K + k0 + scol, &As[c*32 + srow][scol]);
    #pragma unroll
    for (int c = 0; c < 4; c++)
      gload16(Bt + (size_t)(n0 + c*32 + srow) * K + k0 + scol, &Bs[c*32 + srow][scol]);
    __syncthreads();
    #pragma unroll
    for (int kk = 0; kk < 2; kk++){
      bf16x8 a[4], b[4];
      #pragma unroll
      for (int m = 0; m < 4; m++) a[m] = *(const bf16x8*)&As[wr + m*16 + lrow][kk*32 + lk];
      #pragma unroll
      for (int n = 0; n < 4; n++) b[n] = *(const bf16x8*)&Bs[wc + n*16 + lrow][kk*32 + lk];
      #pragma unroll
      for (int m = 0; m < 4; m++)
        #pragma unroll
        for (int n = 0; n < 4; n++)
          acc[m][n] = __builtin_amdgcn_mfma_f32_16x16x32_bf16(a[m], b[n], acc[m][n], 0, 0, 0);
    }
  }
  #pragma unroll
  for (int m = 0; m < 4; m++)
    #pragma unroll
    for (int n = 0; n < 4; n++)
      #pragma unroll
      for (int r = 0; r < 4; r++){
        const int row = m0 + wr + m*16 + (l >> 4)*4 + r;
        const int col = n0 + wc + n*16 + lrow;
        const float v = acc[m][n][r];
        if constexpr (sizeof(OutT) == 2) C[(size_t)row * N + col] = (OutT)f2bf(v);
        else                             C[(size_t)row * N + col] = v;
      }
}

// ---------------- 4. RoPE on Q (with 1/sqrt(HD) scale) and K, in place ----------------
__global__ void k_rope(u16* __restrict__ Q, u16* __restrict__ Kp){
  const int idx = blockIdx.x * 256 + threadIdx.x;  // 4096*32*4 threads
  const int quad = idx & 3;
  const int h = (idx >> 2) & 31;
  const int row = idx >> 7;
  const int s = row & (SS - 1);
  const int i0 = quad * 8;
  u16* q = Q  + (size_t)row * H + h * HD;
  u16* k = Kp + (size_t)row * H + h * HD;
  uint4 q1v = *(const uint4*)(q + i0);
  uint4 q2v = *(const uint4*)(q + i0 + 32);
  uint4 k1v = *(const uint4*)(k + i0);
  uint4 k2v = *(const uint4*)(k + i0 + 32);
  u16* q1 = (u16*)&q1v; u16* q2 = (u16*)&q2v;
  u16* k1 = (u16*)&k1v; u16* k2 = (u16*)&k2v;
  const float sf = (float)s;
  #pragma unroll
  for (int e = 0; e < 8; e++){
    const int i = i0 + e;
    const float inv = exp2f(-0.4152410118609203f * (float)i);  // 10000^(-i/32)
    float rev = sf * inv * 0.15915494309189535f;               // radians -> revolutions
    rev -= floorf(rev);
    const float sn = __builtin_amdgcn_sinf(rev);
    const float cs = __builtin_amdgcn_cosf(rev);
    const float qa = bf2f(q1[e]), qb = bf2f(q2[e]);
    q1[e] = f2bf((qa*cs - qb*sn) * 0.125f);
    q2[e] = f2bf((qb*cs + qa*sn) * 0.125f);
    const float ka = bf2f(k1[e]), kb = bf2f(k2[e]);
    k1[e] = f2bf(ka*cs - kb*sn);
    k2[e] = f2bf(kb*cs + ka*sn);
  }
  *(uint4*)(q + i0)      = q1v;
  *(uint4*)(q + i0 + 32) = q2v;
  *(uint4*)(k + i0)      = k1v;
  *(uint4*)(k + i0 + 32) = k2v;
}

// ---------------- 5. causal flash attention ----------------
// block = 256 thr (4 waves x 16 q-rows), QBLK=64, KVBLK=64.
// Balanced: block x handles q-tiles {x, 31-x} => exactly 33 KV-iterations each.
// 2-phase pipeline: K via global_load_lds, V via reg-staging, double-buffered LDS.
// Swizzles: Qs/Ks col ^= (row&7)*8 (pre-swizzled global src); Vs j ^= 8*(d>>3).
__global__ __launch_bounds__(256, 3) void k_attn(
    const u16* __restrict__ Q, const u16* __restrict__ K,
    const u16* __restrict__ V, u16* __restrict__ O){
  __shared__ __align__(16) u16 Qs[64][64];
  __shared__ __align__(16) u16 Ks[2][64][64];
  __shared__ __align__(16) u16 Vs[2][64][72];   // transposed: Vs[u][d][j'], swizzled j
  __shared__ __align__(16) u16 Ps[4][16][72];   // per-wave P tile, padded
  const int t = threadIdx.x, w = t >> 6, l = t & 63;
  const int x = blockIdx.x, bh = blockIdx.y;
  const int b = bh >> 5, h = bh & 31;
  const u16* kp = K + (size_t)(b*SS) * H + h * HD;
  const u16* vp = V + (size_t)(b*SS) * H + h * HD;
  const int srow = t >> 3, scol = (t & 7) * 8;
  const int sscol = scol ^ ((srow & 7) * 8);     // pre-swizzled global col for Q/K
  const int lrow = l & 15, lk = (l >> 4) * 8;

  #pragma unroll 1
  for (int pp = 0; pp < 2; pp++){
    const int qt = pp ? (31 - x) : x;
    const int q0 = qt * 64;
    const u16* qp = Q + (size_t)(b*SS + q0) * H + h * HD;

    __syncthreads();   // pass boundary: all prior LDS reads done
    // ---- prologue: stage Q, K/V tile 0 ----
    #pragma unroll
    for (int c = 0; c < 2; c++)
      gload16(qp + (size_t)(c*32 + srow) * H + sscol, &Qs[c*32 + srow][scol]);
    #pragma unroll
    for (int c = 0; c < 2; c++)
      gload16(kp + (size_t)(c*32 + srow) * H + sscol, &Ks[0][c*32 + srow][scol]);
    uint4 vv[2];
    #pragma unroll
    for (int c = 0; c < 2; c++)
      vv[c] = *(const uint4*)(vp + (size_t)(c*32 + srow) * H + scol);
    #pragma unroll
    for (int c = 0; c < 2; c++){
      const int j = c*32 + srow;
      const u16* pv = (const u16*)&vv[c];
      #pragma unroll
      for (int e = 0; e < 8; e++){
        const int d = scol + e;
        Vs[0][d][j ^ ((d >> 3) * 8)] = pv[e];
      }
    }
    __syncthreads();

    bf16x8 qa[2];
    qa[0] = *(const bf16x8*)&Qs[w*16 + lrow][(0*32 + lk) ^ ((lrow & 7) * 8)];
    qa[1] = *(const bf16x8*)&Qs[w*16 + lrow][(1*32 + lk) ^ ((lrow & 7) * 8)];

    float mrun[4], lrun[4];
    f32x4 oacc[4] = {};
    #pragma unroll
    for (int r = 0; r < 4; r++){ mrun[r] = -1e30f; lrun[r] = 0.f; }

    for (int jt = 0; jt <= qt; jt++){
      const int u = jt & 1;
      uint4 vvn[2];
      if (jt < qt){   // issue next tile's loads (latency hides under compute)
        const int j0n = (jt + 1) * 64;
        #pragma unroll
        for (int c = 0; c < 2; c++)
          vvn[c] = *(const uint4*)(vp + (size_t)(j0n + c*32 + srow) * H + scol);
        #pragma unroll
        for (int c = 0; c < 2; c++)
          gload16(kp + (size_t)(j0n + c*32 + srow) * H + sscol, &Ks[u^1][c*32 + srow][scol]);
      }

      // ---- S = Q K^T  (16 q-rows x 64 j per wave) ----
      f32x4 sv[4] = {};
      #pragma unroll
      for (int kk = 0; kk < 2; kk++){
        bf16x8 kb[4];
        #pragma unroll
        for (int n = 0; n < 4; n++){
          const int row = n*16 + lrow;
          kb[n] = *(const bf16x8*)&Ks[u][row][(kk*32 + lk) ^ ((row & 7) * 8)];
        }
        #pragma unroll
        for (int n = 0; n < 4; n++)
          sv[n] = __builtin_amdgcn_mfma_f32_16x16x32_bf16(qa[kk], kb[n], sv[n], 0, 0, 0);
      }
      if (jt == qt){  // diagonal tile: mask j > q
        const int qr = w*16 + (l >> 4)*4;
        #pragma unroll
        for (int n = 0; n < 4; n++)
          #pragma unroll
          for (int r = 0; r < 4; r++)
            if (n*16 + lrow > qr + r) sv[n][r] = -1e30f;
      }
      // ---- online softmax (row in 16-lane group, 4 rows per lane) ----
      float tmax[4], fac[4], rsum[4];
      #pragma unroll
      for (int r = 0; r < 4; r++)
        tmax[r] = fmaxf(fmaxf(sv[0][r], sv[1][r]), fmaxf(sv[2][r], sv[3][r]));
      #pragma unroll
      for (int off = 1; off < 16; off <<= 1)
        #pragma unroll
        for (int r = 0; r < 4; r++)
          tmax[r] = fmaxf(tmax[r], __shfl_xor(tmax[r], off, 64));
      #pragma unroll
      for (int r = 0; r < 4; r++){
        const float mn = fmaxf(mrun[r], tmax[r]);
        fac[r] = __expf(mrun[r] - mn);
        mrun[r] = mn;
      }
      #pragma unroll
      for (int n = 0; n < 4; n++)
        #pragma unroll
        for (int r = 0; r < 4; r++)
          sv[n][r] = __expf(sv[n][r] - mrun[r]);
      #pragma unroll
      for (int r = 0; r < 4; r++) rsum[r] = sv[0][r] + sv[1][r] + sv[2][r] + sv[3][r];
      #pragma unroll
      for (int off = 1; off < 16; off <<= 1)
        #pragma unroll
        for (int r = 0; r < 4; r++) rsum[r] += __shfl_xor(rsum[r], off, 64);
      #pragma unroll
      for (int r = 0; r < 4; r++) lrun[r] = lrun[r] * fac[r] + rsum[r];
      #pragma unroll
      for (int n = 0; n < 4; n++)
        #pragma unroll
        for (int r = 0; r < 4; r++) oacc[n][r] *= fac[r];
      // P (C-layout) -> per-wave LDS -> A-frag layout (no barrier: wave-private)
      #pragma unroll
      for (int n = 0; n < 4; n++)
        #pragma unroll
        for (int r = 0; r < 4; r++)
          Ps[w][(l >> 4)*4 + r][n*16 + lrow] = f2bf(sv[n][r]);
      // ---- O += P V ----
      #pragma unroll
      for (int kk = 0; kk < 2; kk++){
        bf16x8 pa = *(const bf16x8*)&Ps[w][lrow][kk*32 + lk];
        #pragma unroll
        for (int n = 0; n < 4; n++){
          const int d = n*16 + lrow;
          bf16x8 vb = *(const bf16x8*)&Vs[u][d][(kk*32 + lk) ^ ((d >> 3) * 8)];
          oacc[n] = __builtin_amdgcn_mfma_f32_16x16x32_bf16(pa, vb, oacc[n], 0, 0, 0);
        }
      }
      if (jt < qt){   // publish next V tile (regs arrived under compute)
        #pragma unroll
        for (int c = 0; c < 2; c++){
          const int j = c*32 + srow;
          const u16* pv = (const u16*)&vvn[c];
          #pragma unroll
          for (int e = 0; e < 8; e++){
            const int d = scol + e;
            Vs[u^1][d][j ^ ((d >> 3) * 8)] = pv[e];
          }
        }
      }
      __syncthreads();  // drains K gload16 (vmcnt) + publishes Vs[u^1]
    }

    u16* op = O + (size_t)(b*SS + q0 + w*16) * H + h * HD;
    #pragma unroll
    for (int r = 0; r < 4; r++){
      const float rl = 1.0f / lrun[r];
      #pragma unroll
      for (int n = 0; n < 4; n++)
        op[(size_t)((l >> 4)*4 + r) * H + n*16 + lrow] = f2bf(oacc[n][r] * rl);
    }
  }
}

extern "C" void kernel_launch(void* const* d_in, const int* in_sizes, int n_in,
                              void* d_out, int out_size, void* d_ws, size_t ws_size,
                              hipStream_t stream){
  (void)in_sizes; (void)n_in; (void)out_size; (void)ws_size;
  const float* hs = (const float*)d_in[0];
  // d_in[1] = attention_mask (causal, implemented analytically)
  const float* wq = (const float*)d_in[2];
  const float* wk = (const float*)d_in[3];
  const float* wv = (const float*)d_in[4];
  const float* wo = (const float*)d_in[5];
  float* out = (float*)d_out;
  char* ws = (char*)d_ws;

  // workspace layout (bytes): Xb 16.8M | Wqt/Wkt/Wvt/Wot 4x8.4M | Vb 16.8M | Ob 16.8M  (~80MB)
  u16* Xb  = (u16*)ws;
  u16* Wqt = (u16*)(ws + (size_t)MM * H * 2);
  u16* Wkt = Wqt + (size_t)H * H;
  u16* Wvt = Wkt + (size_t)H * H;
  u16* Wot = Wvt + (size_t)H * H;
  u16* Vb  = Wot + (size_t)H * H;
  u16* Ob  = Vb  + (size_t)MM * H;
  // Q,K (bf16) live in d_out's 33.5MB until the final GEMM overwrites it
  u16* Qb  = (u16*)d_out;
  u16* Kb  = Qb + (size_t)MM * H;

  k_cvt<<<8192, 256, 0, stream>>>(hs, Xb);
  k_wtrans<<<dim3(64, 64, 4), dim3(32, 8), 0, stream>>>(wq, wk, wv, wo, Wqt, Wkt, Wvt, Wot);
  k_gemm<u16><<<dim3(32, 16, 3), 256, 0, stream>>>(Xb, Wqt, Wkt, Wvt, Qb, Kb, Vb, MM, H, H);
  k_rope<<<2048, 256, 0, stream>>>(Qb, Kb);
  k_attn<<<dim3(16, 64), 256, 0, stream>>>(Qb, Kb, Vb, Ob);
  k_gemm<float><<<dim3(32, 16, 1), 256, 0, stream>>>(Ob, Wot, Wot, Wot, out, out, out, MM, H, H);
}